// Round 13
// baseline (783.582 us; speedup 1.0000x reference)
//
#include <hip/hip_runtime.h>

#define Bb 256
#define Tt 1024
#define NT 96
#define CH 16     // chains per block (MFMA N-dim)
#define CSTR 120  // LDS chain stride in bf16 elems (240B: 16B-aligned, 2-way bank alias max)

typedef __attribute__((ext_vector_type(8))) short bf16x8;
typedef __attribute__((ext_vector_type(4))) float f32x4;

__device__ __forceinline__ unsigned short bf16_rne(float f) {
    unsigned int b = __float_as_uint(f);
    b += 0x7FFFu + ((b >> 16) & 1u);
    return (unsigned short)(b >> 16);
}

// Pre-pass: eh = exp(h); removes 24 v_exp_f32 per main-loop step.
__global__ void exp_prepass(const float4* __restrict__ src, float4* __restrict__ dst, int n4) {
    int idx = blockIdx.x * blockDim.x + threadIdx.x;
    int stride = gridDim.x * blockDim.x;
    for (int i = idx; i < n4; i += stride) {
        float4 v = src[i];
        dst[i] = make_float4(__expf(v.x), __expf(v.y), __expf(v.z), __expf(v.w));
    }
}

// CRF forward via MFMA: 16 chains/block, ONE wave, zero barriers.
// Scale algebra (r12 bug fixed): p tracks p_true * 2^{-9*nsteps} / prod(mx).
// Every applied multiplier must be subtracted in log from Mloc:
//   renorm applies ui=rcp(mx)  => Mloc -= log(ui)   (== +log mx; r12 had -log mx)
//   each unmasked step applies 2^-9 (folded in E')   => out += 9*ln2*L at the end.
// k-slot mapping of A/B frags is provably irrelevant (same sigma for A and B
// cancels by permutation-invariance of the k-sum) — r11/r12 identical absmax
// confirmed this. C/D: col=lane&15 (chain), row=4*(lane>>4)+reg (m89).
template <bool PRE>
__global__ __attribute__((amdgpu_flat_work_group_size(64, 64),
                          amdgpu_waves_per_eu(1, 1)))
void crf_mfma_kernel(const float* __restrict__ hsrc,
                     const int* __restrict__ lengths,
                     const float* __restrict__ trans,
                     float* __restrict__ out) {
    const int b0   = blockIdx.x * CH;
    const int lane = threadIdx.x;
    const int c    = lane & 15;
    const int g    = lane >> 4;
    const int L    = lengths[b0 + c];

    __shared__ __align__(16) short pbuf[CH * CSTR];

    // A-frags, contiguous k: element e of tile (mt,kt) = E'[16mt+c][32kt+8g+e]
    bf16x8 afrag[6][3];
    #pragma unroll
    for (int mt = 0; mt < 6; ++mt) {
        const float* row = trans + (16 * mt + c) * NT;
        #pragma unroll
        for (int kt = 0; kt < 3; ++kt) {
            const float4 t0 = *(const float4*)(row + 32 * kt + 8 * g);
            const float4 t1 = *(const float4*)(row + 32 * kt + 8 * g + 4);
            bf16x8 f;
            f[0] = (short)bf16_rne(__expf(t0.x) * 0.001953125f);
            f[1] = (short)bf16_rne(__expf(t0.y) * 0.001953125f);
            f[2] = (short)bf16_rne(__expf(t0.z) * 0.001953125f);
            f[3] = (short)bf16_rne(__expf(t0.w) * 0.001953125f);
            f[4] = (short)bf16_rne(__expf(t1.x) * 0.001953125f);
            f[5] = (short)bf16_rne(__expf(t1.y) * 0.001953125f);
            f[6] = (short)bf16_rne(__expf(t1.z) * 0.001953125f);
            f[7] = (short)bf16_rne(__expf(t1.w) * 0.001953125f);
            afrag[mt][kt] = f;
        }
    }

    // p_0 = delta(start_tag=94): mt=5, 4g+r=14 -> g=3, r=2 (all chains)
    float wC[6][4];
    #pragma unroll
    for (int mt = 0; mt < 6; ++mt)
        #pragma unroll
        for (int r = 0; r < 4; ++r) wC[mt][r] = 0.0f;
    if (g == 3) wC[5][2] = 1.0f;

    // initial LDS image of p_0 (exact: 1.0/0.0)
    #pragma unroll
    for (int mt = 0; mt < 6; ++mt) {
        unsigned int p01 = (__float_as_uint(wC[mt][1]) & 0xFFFF0000u) |
                           (__float_as_uint(wC[mt][0]) >> 16);
        unsigned int p23 = (__float_as_uint(wC[mt][3]) & 0xFFFF0000u) |
                           (__float_as_uint(wC[mt][2]) >> 16);
        *(uint2*)&pbuf[c * CSTR + 16 * mt + 4 * g] = make_uint2(p01, p23);
    }

    // h stream: lane reads rows 16mt+4g..+3 of chain c (matches C-layout rows)
    const float* hb = hsrc + ((size_t)(b0 + c) * Tt) * NT + 4 * g;
    float4 hpA[6], hpB[6];
    #pragma unroll
    for (int mt = 0; mt < 6; ++mt) hpA[mt] = *(const float4*)(hb + (size_t)0 * NT + 16 * mt);
    #pragma unroll
    for (int mt = 0; mt < 6; ++mt) hpB[mt] = *(const float4*)(hb + (size_t)1 * NT + 16 * mt);

    float Mloc = 0.0f;

#define STEPX(HP, T_)                                                          \
    {                                                                          \
        bf16x8 bfr[3];                                                         \
        _Pragma("unroll")                                                      \
        for (int kt = 0; kt < 3; ++kt)                                         \
            bfr[kt] = *(const bf16x8*)&pbuf[c * CSTR + 32 * kt + 8 * g];       \
        f32x4 acc[6];                                                          \
        _Pragma("unroll")                                                      \
        for (int mt = 0; mt < 6; ++mt) {                                       \
            f32x4 a = {0.f, 0.f, 0.f, 0.f};                                    \
            a = __builtin_amdgcn_mfma_f32_16x16x32_bf16(afrag[mt][0], bfr[0], a, 0, 0, 0); \
            a = __builtin_amdgcn_mfma_f32_16x16x32_bf16(afrag[mt][1], bfr[1], a, 0, 0, 0); \
            a = __builtin_amdgcn_mfma_f32_16x16x32_bf16(afrag[mt][2], bfr[2], a, 0, 0, 0); \
            acc[mt] = a;                                                       \
        }                                                                      \
        const bool msk = ((T_) < L);                                           \
        _Pragma("unroll")                                                      \
        for (int mt = 0; mt < 6; ++mt) {                                       \
            const float e0 = PRE ? HP[mt].x : __expf(HP[mt].x);                \
            const float e1 = PRE ? HP[mt].y : __expf(HP[mt].y);                \
            const float e2 = PRE ? HP[mt].z : __expf(HP[mt].z);                \
            const float e3 = PRE ? HP[mt].w : __expf(HP[mt].w);                \
            wC[mt][0] = msk ? acc[mt][0] * e0 : wC[mt][0];                     \
            wC[mt][1] = msk ? acc[mt][1] * e1 : wC[mt][1];                     \
            wC[mt][2] = msk ? acc[mt][2] * e2 : wC[mt][2];                     \
            wC[mt][3] = msk ? acc[mt][3] * e3 : wC[mt][3];                     \
        }                                                                      \
        if (((T_) & 15) == 15) {                                               \
            float mx = wC[0][0];                                               \
            _Pragma("unroll")                                                  \
            for (int mt = 0; mt < 6; ++mt) {                                   \
                mx = fmaxf(mx, wC[mt][0]); mx = fmaxf(mx, wC[mt][1]);          \
                mx = fmaxf(mx, wC[mt][2]); mx = fmaxf(mx, wC[mt][3]);          \
            }                                                                  \
            mx = fmaxf(mx, __shfl_xor(mx, 16, 64));                            \
            mx = fmaxf(mx, __shfl_xor(mx, 32, 64));                            \
            const float ui = __builtin_amdgcn_rcpf(mx);                        \
            Mloc -= __logf(ui);   /* compensate the APPLIED factor (r12 fix) */\
            _Pragma("unroll")                                                  \
            for (int mt = 0; mt < 6; ++mt) {                                   \
                wC[mt][0] *= ui; wC[mt][1] *= ui;                              \
                wC[mt][2] *= ui; wC[mt][3] *= ui;                              \
            }                                                                  \
        }                                                                      \
        _Pragma("unroll")                                                      \
        for (int mt = 0; mt < 6; ++mt) {                                       \
            unsigned int p01 = (__float_as_uint(wC[mt][1]) & 0xFFFF0000u) |    \
                               (__float_as_uint(wC[mt][0]) >> 16);             \
            unsigned int p23 = (__float_as_uint(wC[mt][3]) & 0xFFFF0000u) |    \
                               (__float_as_uint(wC[mt][2]) >> 16);             \
            *(uint2*)&pbuf[c * CSTR + 16 * mt + 4 * g] = make_uint2(p01, p23); \
        }                                                                      \
    }

    for (int t = 0; t < Tt; t += 2) {
        STEPX(hpA, t);
        {
            const size_t tn = (size_t)((t + 2 > Tt - 1) ? (Tt - 1) : (t + 2));
            #pragma unroll
            for (int mt = 0; mt < 6; ++mt)
                hpA[mt] = *(const float4*)(hb + tn * NT + 16 * mt);
        }
        STEPX(hpB, t + 1);
        {
            const size_t tn = (size_t)((t + 3 > Tt - 1) ? (Tt - 1) : (t + 3));
            #pragma unroll
            for (int mt = 0; mt < 6; ++mt)
                hpB[mt] = *(const float4*)(hb + tn * NT + 16 * mt);
        }
    }
#undef STEPX

    // out[b0+c] = Mloc + 9*ln2*L (per-step 2^-9 in E', L unmasked steps)
    //           + log( sum_i p[i] * exp(trans[end_tag=95][i]) )
    float ft = 0.0f;
    #pragma unroll
    for (int mt = 0; mt < 6; ++mt) {
        const float4 e4 = *(const float4*)(trans + 95 * NT + 16 * mt + 4 * g);
        ft += wC[mt][0] * __expf(e4.x);
        ft += wC[mt][1] * __expf(e4.y);
        ft += wC[mt][2] * __expf(e4.z);
        ft += wC[mt][3] * __expf(e4.w);
    }
    ft += __shfl_xor(ft, 16, 64);
    ft += __shfl_xor(ft, 32, 64);
    if (lane < CH)
        out[b0 + lane] = Mloc + 6.23832462503951f * (float)L + __logf(ft);
}

extern "C" void kernel_launch(void* const* d_in, const int* in_sizes, int n_in,
                              void* d_out, int out_size, void* d_ws, size_t ws_size,
                              hipStream_t stream) {
    const float* h       = (const float*)d_in[0];
    const int*   lengths = (const int*)d_in[1];
    const float* trans   = (const float*)d_in[2];
    float*       out     = (float*)d_out;
    (void)in_sizes; (void)n_in; (void)out_size;

    const size_t need = (size_t)Bb * Tt * NT * sizeof(float);  // 100,663,296 B
    if (ws_size >= need) {
        const int n4 = Bb * Tt * NT / 4;
        exp_prepass<<<2048, 256, 0, stream>>>((const float4*)h, (float4*)d_ws, n4);
        crf_mfma_kernel<true><<<Bb / CH, 64, 0, stream>>>((const float*)d_ws, lengths, trans, out);
    } else {
        crf_mfma_kernel<false><<<Bb / CH, 64, 0, stream>>>(h, lengths, trans, out);
    }
}

// Round 14
// 448.272 us; speedup vs baseline: 1.7480x; 1.7480x over previous
//
#include <hip/hip_runtime.h>
#include <type_traits>

#define Bb 256
#define Tt 1024
#define NT 96
#define CH 16
#define CSTR 120

typedef __attribute__((ext_vector_type(8))) short bf16x8;
typedef __attribute__((ext_vector_type(4))) float f32x4;

__device__ __forceinline__ unsigned short bf16_rne(float f) {
    unsigned int b = __float_as_uint(f);
    b += 0x7FFFu + ((b >> 16) & 1u);
    return (unsigned short)(b >> 16);
}

// Pre-pass: ws <- packed bf16(exp(h)) (50 MB), halves main-loop h-regs + kills in-loop exp.
__global__ void exp_prepass_bf16(const float4* __restrict__ src,
                                 uint2* __restrict__ dst, int n4) {
    int idx = blockIdx.x * blockDim.x + threadIdx.x;
    int stride = gridDim.x * blockDim.x;
    for (int i = idx; i < n4; i += stride) {
        float4 v = src[i];
        uint2 o;
        o.x = (unsigned)bf16_rne(__expf(v.x)) | ((unsigned)bf16_rne(__expf(v.y)) << 16);
        o.y = (unsigned)bf16_rne(__expf(v.z)) | ((unsigned)bf16_rne(__expf(v.w)) << 16);
        dst[i] = o;
    }
}

// CRF forward via MFMA: 16 chains/block, ONE wave, zero barriers, state-in-LDS.
// r13 lesson: 132-VGPR alloc ceiling with waves_per_eu(1,1); design UNDER it:
// no wC (freeze = skip-write; renorm rescales LDS image), eh packed bf16,
// 4-deep hp rotation (3-step load slack covers L2/L3 latency, no TLP needed).
// Scale algebra (r12-verified): Mloc += log(mx) per renorm; out += 9ln2*L for
// the per-step 2^-9 folded into E'. k-slot mapping cancels (same sigma A & B).
template <bool PRE>
__global__ __attribute__((amdgpu_flat_work_group_size(64, 64),
                          amdgpu_waves_per_eu(1, 1)))
void crf_mfma_kernel(const void* __restrict__ hsrc,
                     const int* __restrict__ lengths,
                     const float* __restrict__ trans,
                     float* __restrict__ out) {
    const int b0   = blockIdx.x * CH;
    const int lane = threadIdx.x;
    const int c    = lane & 15;
    const int g    = lane >> 4;
    const int L    = lengths[b0 + c];

    __shared__ __align__(16) short pbuf[CH * CSTR];

    // A-frags: E' = exp(trans)*2^-9; elem e of (mt,kt) = E'[16mt+c][32kt+8g+e]
    bf16x8 afrag[6][3];
    #pragma unroll
    for (int mt = 0; mt < 6; ++mt) {
        const float* row = trans + (16 * mt + c) * NT;
        #pragma unroll
        for (int kt = 0; kt < 3; ++kt) {
            const float4 t0 = *(const float4*)(row + 32 * kt + 8 * g);
            const float4 t1 = *(const float4*)(row + 32 * kt + 8 * g + 4);
            bf16x8 f;
            f[0] = (short)bf16_rne(__expf(t0.x) * 0.001953125f);
            f[1] = (short)bf16_rne(__expf(t0.y) * 0.001953125f);
            f[2] = (short)bf16_rne(__expf(t0.z) * 0.001953125f);
            f[3] = (short)bf16_rne(__expf(t0.w) * 0.001953125f);
            f[4] = (short)bf16_rne(__expf(t1.x) * 0.001953125f);
            f[5] = (short)bf16_rne(__expf(t1.y) * 0.001953125f);
            f[6] = (short)bf16_rne(__expf(t1.z) * 0.001953125f);
            f[7] = (short)bf16_rne(__expf(t1.w) * 0.001953125f);
            afrag[mt][kt] = f;
        }
    }

    // p_0 = delta(start_tag=94): zero all own slots, then (mt=5,g=3) slot gets
    // tags 92..95 = {0,0,1,0} -> uint2(0, 0x3F80)
    #pragma unroll
    for (int mt = 0; mt < 6; ++mt)
        *(uint2*)&pbuf[c * CSTR + 16 * mt + 4 * g] = make_uint2(0u, 0u);
    if (g == 3)
        *(uint2*)&pbuf[c * CSTR + 16 * 5 + 4 * 3] = make_uint2(0u, 0x00003F80u);

    using HPT = typename std::conditional<PRE, uint2, float4>::type;
    const unsigned short* ebp = (const unsigned short*)hsrc + (size_t)(b0 + c) * Tt * NT + 4 * g;
    const float*          hbp = (const float*)hsrc          + (size_t)(b0 + c) * Tt * NT + 4 * g;

#define RELOAD(HP, TN)                                                         \
    {                                                                          \
        int tn_ = (TN); if (tn_ > Tt - 1) tn_ = Tt - 1;                        \
        _Pragma("unroll")                                                      \
        for (int mt = 0; mt < 6; ++mt) {                                       \
            if constexpr (PRE)                                                 \
                HP[mt] = *(const uint2*)(ebp + (size_t)tn_ * NT + 16 * mt);    \
            else                                                               \
                HP[mt] = *(const float4*)(hbp + (size_t)tn_ * NT + 16 * mt);   \
        }                                                                      \
    }

    HPT hp0[6], hp1[6], hp2[6], hp3[6];
    RELOAD(hp0, 0) RELOAD(hp1, 1) RELOAD(hp2, 2) RELOAD(hp3, 3)

    float Mloc = 0.0f;

#define PACKW(W0, W1) ((__float_as_uint(W1) & 0xFFFF0000u) | (__float_as_uint(W0) >> 16))

#define STEPX(HP, T_)                                                          \
    {                                                                          \
        bf16x8 bfr[3];                                                         \
        _Pragma("unroll")                                                      \
        for (int kt = 0; kt < 3; ++kt)                                         \
            bfr[kt] = *(const bf16x8*)&pbuf[c * CSTR + 32 * kt + 8 * g];       \
        f32x4 acc[6];                                                          \
        _Pragma("unroll")                                                      \
        for (int mt = 0; mt < 6; ++mt) {                                       \
            f32x4 a = {0.f, 0.f, 0.f, 0.f};                                    \
            a = __builtin_amdgcn_mfma_f32_16x16x32_bf16(afrag[mt][0], bfr[0], a, 0, 0, 0); \
            a = __builtin_amdgcn_mfma_f32_16x16x32_bf16(afrag[mt][1], bfr[1], a, 0, 0, 0); \
            a = __builtin_amdgcn_mfma_f32_16x16x32_bf16(afrag[mt][2], bfr[2], a, 0, 0, 0); \
            acc[mt] = a;                                                       \
        }                                                                      \
        const bool msk = ((T_) < L);                                           \
        float w[6][4];                                                         \
        _Pragma("unroll")                                                      \
        for (int mt = 0; mt < 6; ++mt) {                                       \
            float e0, e1, e2, e3;                                              \
            if constexpr (PRE) {                                               \
                e0 = __uint_as_float(HP[mt].x << 16);                          \
                e1 = __uint_as_float(HP[mt].x & 0xFFFF0000u);                  \
                e2 = __uint_as_float(HP[mt].y << 16);                          \
                e3 = __uint_as_float(HP[mt].y & 0xFFFF0000u);                  \
            } else {                                                           \
                e0 = __expf(HP[mt].x); e1 = __expf(HP[mt].y);                  \
                e2 = __expf(HP[mt].z); e3 = __expf(HP[mt].w);                  \
            }                                                                  \
            w[mt][0] = acc[mt][0] * e0; w[mt][1] = acc[mt][1] * e1;            \
            w[mt][2] = acc[mt][2] * e2; w[mt][3] = acc[mt][3] * e3;            \
        }                                                                      \
        if (((T_) & 15) == 15) {                                               \
            float pv[3][8];                                                    \
            _Pragma("unroll")                                                  \
            for (int kt = 0; kt < 3; ++kt)                                     \
                _Pragma("unroll")                                              \
                for (int e = 0; e < 8; ++e)                                    \
                    pv[kt][e] = __uint_as_float(((unsigned)(unsigned short)bfr[kt][e]) << 16); \
            float mx;                                                          \
            if (msk) {                                                         \
                mx = w[0][0];                                                  \
                _Pragma("unroll")                                              \
                for (int mt = 0; mt < 6; ++mt) {                               \
                    mx = fmaxf(fmaxf(mx, w[mt][0]), w[mt][1]);                 \
                    mx = fmaxf(fmaxf(mx, w[mt][2]), w[mt][3]);                 \
                }                                                              \
            } else {                                                           \
                mx = pv[0][0];                                                 \
                _Pragma("unroll")                                              \
                for (int kt = 0; kt < 3; ++kt)                                 \
                    _Pragma("unroll")                                          \
                    for (int e = 0; e < 8; ++e) mx = fmaxf(mx, pv[kt][e]);     \
            }                                                                  \
            mx = fmaxf(mx, __shfl_xor(mx, 16, 64));                            \
            mx = fmaxf(mx, __shfl_xor(mx, 32, 64));                            \
            const float ui = __builtin_amdgcn_rcpf(mx);                        \
            Mloc += __logf(mx);                                                \
            if (msk) {                                                         \
                _Pragma("unroll")                                              \
                for (int mt = 0; mt < 6; ++mt) {                               \
                    const float s0 = w[mt][0] * ui, s1 = w[mt][1] * ui;        \
                    const float s2 = w[mt][2] * ui, s3 = w[mt][3] * ui;        \
                    *(uint2*)&pbuf[c * CSTR + 16 * mt + 4 * g] =               \
                        make_uint2(PACKW(s0, s1), PACKW(s2, s3));              \
                }                                                              \
            } else {                                                           \
                _Pragma("unroll")                                              \
                for (int kt = 0; kt < 3; ++kt) {                               \
                    bf16x8 f;                                                  \
                    _Pragma("unroll")                                          \
                    for (int e = 0; e < 8; ++e)                                \
                        f[e] = (short)(__float_as_uint(pv[kt][e] * ui) >> 16); \
                    *(bf16x8*)&pbuf[c * CSTR + 32 * kt + 8 * g] = f;           \
                }                                                              \
            }                                                                  \
        } else if (msk) {                                                      \
            _Pragma("unroll")                                                  \
            for (int mt = 0; mt < 6; ++mt)                                     \
                *(uint2*)&pbuf[c * CSTR + 16 * mt + 4 * g] =                   \
                    make_uint2(PACKW(w[mt][0], w[mt][1]),                      \
                               PACKW(w[mt][2], w[mt][3]));                     \
        }                                                                      \
    }

    for (int t = 0; t < Tt; t += 4) {
        STEPX(hp0, t)     RELOAD(hp0, t + 4)
        STEPX(hp1, t + 1) RELOAD(hp1, t + 5)
        STEPX(hp2, t + 2) RELOAD(hp2, t + 6)
        STEPX(hp3, t + 3) RELOAD(hp3, t + 7)
    }
#undef STEPX
#undef RELOAD
#undef PACKW

    // out[b0+c] = Mloc + 9ln2*L + log( sum_i p[i]*exp(trans[95][i]) )
    float ft = 0.0f;
    #pragma unroll
    for (int kt = 0; kt < 3; ++kt) {
        const bf16x8 pf = *(const bf16x8*)&pbuf[c * CSTR + 32 * kt + 8 * g];
        const float4 t0 = *(const float4*)(trans + 95 * NT + 32 * kt + 8 * g);
        const float4 t1 = *(const float4*)(trans + 95 * NT + 32 * kt + 8 * g + 4);
        ft += __uint_as_float(((unsigned)(unsigned short)pf[0]) << 16) * __expf(t0.x);
        ft += __uint_as_float(((unsigned)(unsigned short)pf[1]) << 16) * __expf(t0.y);
        ft += __uint_as_float(((unsigned)(unsigned short)pf[2]) << 16) * __expf(t0.z);
        ft += __uint_as_float(((unsigned)(unsigned short)pf[3]) << 16) * __expf(t0.w);
        ft += __uint_as_float(((unsigned)(unsigned short)pf[4]) << 16) * __expf(t1.x);
        ft += __uint_as_float(((unsigned)(unsigned short)pf[5]) << 16) * __expf(t1.y);
        ft += __uint_as_float(((unsigned)(unsigned short)pf[6]) << 16) * __expf(t1.z);
        ft += __uint_as_float(((unsigned)(unsigned short)pf[7]) << 16) * __expf(t1.w);
    }
    ft += __shfl_xor(ft, 16, 64);
    ft += __shfl_xor(ft, 32, 64);
    if (lane < CH)
        out[b0 + lane] = Mloc + 6.23832462503951f * (float)L + __logf(ft);
}

extern "C" void kernel_launch(void* const* d_in, const int* in_sizes, int n_in,
                              void* d_out, int out_size, void* d_ws, size_t ws_size,
                              hipStream_t stream) {
    const float* h       = (const float*)d_in[0];
    const int*   lengths = (const int*)d_in[1];
    const float* trans   = (const float*)d_in[2];
    float*       out     = (float*)d_out;
    (void)in_sizes; (void)n_in; (void)out_size;

    const size_t need = (size_t)Bb * Tt * NT * sizeof(unsigned short);  // 50,331,648 B
    if (ws_size >= need) {
        const int n4 = Bb * Tt * NT / 4;
        exp_prepass_bf16<<<2048, 256, 0, stream>>>((const float4*)h, (uint2*)d_ws, n4);
        crf_mfma_kernel<true><<<Bb / CH, 64, 0, stream>>>((const void*)d_ws, lengths, trans, out);
    } else {
        crf_mfma_kernel<false><<<Bb / CH, 64, 0, stream>>>((const void*)h, lengths, trans, out);
    }
}